// Round 2
// baseline (21927.966 us; speedup 1.0000x reference)
//
#include <hip/hip_runtime.h>
#include <math.h>

// ResidualVQ fused forward, MI355X (gfx950) — round 2.
//
// Algebraic restructure: z_i = z_e.WdT_i + hv_i - sum_{j<i} zq_j.G[j][i],
// G[j][i] = WuT_j.WdT_i (16x16). Eliminates the proj_up residual update
// (phase C) and the 1024-dim per-thread residual that caused round-1's
// 31 GB scratch-spill traffic.
//
// Full fp64 chain (round 1 proved the harness reference is fp64-exact:
// 0 code flips in 262144 with fp64, threshold 20.48 forbids any flip).
//
// ws layout (doubles):
//   [0..1]   loss accumulator
//   [16 ..]  cbn: 8192 rows x 18 (slots 0..15 = normalized code, pair p at
//            slot ((p+k)&7)*2 [bank rotation baked in]; slot16 = |cbn|^2)
//   [+147456] G: [j][i][a][b] full 8x8x16x16 (only j<i written/read)
//   [+16384]  hv: [i][b] 8x16
#define CBN_OFF 16
#define G_OFF   (16 + 147456)
#define HV_OFF  (G_OFF + 16384)

__global__ void __launch_bounds__(64) rvq_zero(double* w) {
    if (threadIdx.x < 2) w[threadIdx.x] = 0.0;
}

__global__ void __launch_bounds__(256) rvq_prep_cbn(const float* __restrict__ cb,
                                                    double* __restrict__ cbn) {
    const int idx = blockIdx.x * 256 + threadIdx.x;   // 0..8191 = l*1024+k
    const float4* cp = (const float4*)(cb + (size_t)idx * 16);
    const float4 a0 = cp[0], a1 = cp[1], a2 = cp[2], a3 = cp[3];
    const float cf[16] = {a0.x,a0.y,a0.z,a0.w, a1.x,a1.y,a1.z,a1.w,
                          a2.x,a2.y,a2.z,a2.w, a3.x,a3.y,a3.z,a3.w};
    double v[16]; double n = 0.0;
#pragma unroll
    for (int c = 0; c < 16; ++c) { v[c] = (double)cf[c]; n = fma(v[c], v[c], n); }
    const double iv = 1.0 / fmax(sqrt(n), 1e-12);
    double* row = cbn + (size_t)idx * 18;
    double c2 = 0.0;
#pragma unroll
    for (int p = 0; p < 8; ++p) {
        const double x = v[2*p] * iv, y = v[2*p+1] * iv;
        c2 = fma(x, x, c2); c2 = fma(y, y, c2);
        const int slot = ((p + idx) & 7) * 2;
        row[slot] = x; row[slot + 1] = y;
    }
    row[16] = c2; row[17] = 0.0;
}

__global__ void __launch_bounds__(256) rvq_prep_g(const float* __restrict__ Wu,
                                                  const float* __restrict__ Wd,
                                                  double* __restrict__ G) {
    const int j = blockIdx.x >> 3, i = blockIdx.x & 7;
    if (j >= i) return;
    const int t = threadIdx.x, a = t >> 4, b = t & 15;
    const float* up = Wu + (size_t)j * 16384 + a;                 // stride 16
    const float* dp = Wd + (size_t)i * 16384 + (size_t)b * 1024;  // stride 1
    double s0 = 0, s1 = 0, s2 = 0, s3 = 0;
    for (int d = 0; d < 1024; d += 4) {
        s0 = fma((double)up[(d + 0) * 16], (double)dp[d + 0], s0);
        s1 = fma((double)up[(d + 1) * 16], (double)dp[d + 1], s1);
        s2 = fma((double)up[(d + 2) * 16], (double)dp[d + 2], s2);
        s3 = fma((double)up[(d + 3) * 16], (double)dp[d + 3], s3);
    }
    G[(size_t)(j * 8 + i) * 256 + t] = (s0 + s1) + (s2 + s3);
}

__global__ void __launch_bounds__(128) rvq_prep_h(const float* __restrict__ Wd,
                                                  const float* __restrict__ bd,
                                                  const float* __restrict__ bu,
                                                  double* __restrict__ hv) {
    const int t = threadIdx.x;           // 128 threads: t = i*16 + b
    const int i = t >> 4, b = t & 15;
    const float* dp = Wd + (size_t)i * 16384 + (size_t)b * 1024;
    double s = 0.0;
    for (int d = 0; d < 1024; ++d) {
        double sb = 0.0;
        for (int j = 0; j < i; ++j) sb += (double)bu[j * 1024 + d];
        s = fma(sb, (double)dp[d], s);
    }
    hv[t] = (double)bd[t] - s;
}

// Main: 2048 blocks x 256 threads. Group g = t>>5 owns block-local tokens
// 2g, 2g+1. Lane m = t&31 owns dims d = m+32j in the big GEMM.
__global__ void __launch_bounds__(256, 2) rvq_main(
    const float* __restrict__ z_e, const float* __restrict__ Wd,
    const float* __restrict__ cb,
    const double* __restrict__ cbn, const double* __restrict__ G,
    const double* __restrict__ hv, double* __restrict__ wacc,
    float* __restrict__ out0, float* __restrict__ out1)
{
    __shared__ double wds[4608];    // 36864 B: weight/codebook staging (18-stride rotated)
    __shared__ double ybuf[2048];   // 16 tokens x 128 (z for all 8 layers)
    __shared__ double lred[8];

    const int t = threadIdx.x, g = t >> 5, m = t & 31;
    const int tok0 = blockIdx.x * 16 + g * 2;

    // z_e rows (exact fp32 inputs) — 64 VGPRs, dead after the big GEMM
    float zef[2][32];
#pragma unroll
    for (int h = 0; h < 2; ++h) {
        const float* zp = z_e + (size_t)(tok0 + h) * 1024 + m;
#pragma unroll
        for (int jj = 0; jj < 32; ++jj) zef[h][jj] = zp[32 * jj];
    }

    // ============ big GEMM: ybuf[tok][i*16+c] = z_e . WdT_i + hv_i ============
#pragma unroll 1
    for (int i = 0; i < 8; ++i) {
        double pa[2][16];
#pragma unroll
        for (int h = 0; h < 2; ++h)
#pragma unroll
            for (int c = 0; c < 16; ++c) pa[h][c] = 0.0;
#pragma unroll
        for (int ch = 0; ch < 4; ++ch) {
            __syncthreads();
            {   // stage WdT chunk: row dloc=t holds Wd[i][c][256ch+t], c=0..15, fp64
                const float* wp = Wd + (size_t)i * 16384 + 256 * ch + t;
                float wv[16];
#pragma unroll
                for (int c = 0; c < 16; ++c) wv[c] = wp[c * 1024];
                double* row = &wds[t * 18];
#pragma unroll
                for (int p = 0; p < 8; ++p) {
                    const int slot = ((p + t) & 7) * 2;
                    *(double2*)&row[slot] =
                        make_double2((double)wv[2 * p], (double)wv[2 * p + 1]);
                }
            }
            __syncthreads();
#pragma unroll
            for (int jj = 0; jj < 8; ++jj) {
                const int j = ch * 8 + jj;
                const int r = m + 32 * jj;
                const double rv0 = (double)zef[0][j];
                const double rv1 = (double)zef[1][j];
                const double* row = &wds[r * 18];
#pragma unroll
                for (int p = 0; p < 8; ++p) {   // rotation key: r&7 == m&7
                    const double2 w2 = *(const double2*)&row[((p + m) & 7) * 2];
                    pa[0][2*p]     = fma(rv0, w2.x, pa[0][2*p]);
                    pa[0][2*p + 1] = fma(rv0, w2.y, pa[0][2*p + 1]);
                    pa[1][2*p]     = fma(rv1, w2.x, pa[1][2*p]);
                    pa[1][2*p + 1] = fma(rv1, w2.y, pa[1][2*p + 1]);
                }
            }
        }
        // reduce partials across the 32 lanes of each group (stride-17 buffer)
#pragma unroll
        for (int h = 0; h < 2; ++h) {
            __syncthreads();
            {
                double* row = &wds[t * 17];
#pragma unroll
                for (int c = 0; c < 16; ++c) row[c] = pa[h][c];
            }
            __syncthreads();
            if (t < 128) {
                const int tokg = t >> 4, c = t & 15;
                double s = 0.0;
#pragma unroll
                for (int idx = 0; idx < 32; ++idx) {
                    const int mm = (idx + tokg * 8) & 31;   // bank spread per tokg
                    s += wds[(tokg * 32 + mm) * 17 + c];
                }
                ybuf[(tokg * 2 + h) * 128 + i * 16 + c] = s + hv[i * 16 + c];
            }
        }
    }
    __syncthreads();

    // ============ layer loop: normalize, argmin, output, corrections ============
    double acc_loss = 0.0;
#pragma unroll 1
    for (int l = 0; l < 8; ++l) {
        double znd[2][16];
#pragma unroll
        for (int h = 0; h < 2; ++h) {
            const double* zr = &ybuf[(g * 2 + h) * 128 + l * 16];
            double n2 = 0.0;
#pragma unroll
            for (int c = 0; c < 16; ++c) { const double v = zr[c]; znd[h][c] = v; n2 = fma(v, v, n2); }
            const double iv = 1.0 / fmax(sqrt(n2), 1e-12);
#pragma unroll
            for (int c = 0; c < 16; ++c) znd[h][c] *= iv;
        }
        double bs0 = 1e300, bs1 = 1e300;
        int bk0 = 0, bk1 = 0;
#pragma unroll
        for (int q = 0; q < 4; ++q) {
            __syncthreads();
            {   // copy 256 pre-normalized, pre-rotated fp64 code rows from ws
                const double* src = cbn + (size_t)(l * 1024 + q * 256 + t) * 18;
                double* row = &wds[t * 18];
#pragma unroll
                for (int u = 0; u < 9; ++u) {
                    const int su = (u < 8) ? ((u + t) & 7) * 2 : 16;
                    *(double2*)&row[su] = *(const double2*)&src[su];
                }
            }
            __syncthreads();
#pragma unroll
            for (int kk = 0; kk < 8; ++kk) {
                const int kl = m + 32 * kk;
                const double* row = &wds[kl * 18];
                double d0 = 0.0, d1 = 0.0;
#pragma unroll
                for (int p = 0; p < 8; ++p) {   // rotation key: kl&7 == m&7
                    const double2 cv = *(const double2*)&row[((p + m) & 7) * 2];
                    d0 = fma(cv.x, znd[0][2*p], d0); d0 = fma(cv.y, znd[0][2*p + 1], d0);
                    d1 = fma(cv.x, znd[1][2*p], d1); d1 = fma(cv.y, znd[1][2*p + 1], d1);
                }
                const double cn2 = row[16];
                const double s0 = fma(-2.0, d0, cn2);
                const double s1 = fma(-2.0, d1, cn2);
                const int k = q * 256 + kl;
                if (s0 < bs0) { bs0 = s0; bk0 = k; }
                if (s1 < bs1) { bs1 = s1; bk1 = k; }
            }
        }
        // 32-lane butterfly (never crosses the 32-lane group boundary),
        // lexicographic (dist, k) merge == np.argmin first-min tie-break
#pragma unroll
        for (int off = 1; off < 32; off <<= 1) {
            const double o0 = __shfl_xor(bs0, off); const int p0 = __shfl_xor(bk0, off);
            if (o0 < bs0 || (o0 == bs0 && p0 < bk0)) { bs0 = o0; bk0 = p0; }
            const double o1 = __shfl_xor(bs1, off); const int p1 = __shfl_xor(bk1, off);
            if (o1 < bs1 || (o1 == bs1 && p1 < bk1)) { bs1 = o1; bk1 = p1; }
        }
        // gather RAW codebook rows; write outputs (lane 0 of group)
        double zqd[2][16];
#pragma unroll
        for (int h = 0; h < 2; ++h) {
            const int bk = h ? bk1 : bk0;
            const float4* qp = (const float4*)(cb + ((size_t)l * 1024 + bk) * 16);
            const float4 q0 = qp[0], q1 = qp[1], q2 = qp[2], q3 = qp[3];
            const float qf[16] = {q0.x,q0.y,q0.z,q0.w, q1.x,q1.y,q1.z,q1.w,
                                  q2.x,q2.y,q2.z,q2.w, q3.x,q3.y,q3.z,q3.w};
#pragma unroll
            for (int c = 0; c < 16; ++c) zqd[h][c] = (double)qf[c];
            if (m == 0) {
                float* op = out0 + (size_t)(tok0 + h) * 128 + l * 16;
                ((float4*)op)[0] = q0; ((float4*)op)[1] = q1;
                ((float4*)op)[2] = q2; ((float4*)op)[3] = q3;
                out1[(size_t)(tok0 + h) * 8 + l] = (float)bk;
            }
        }
        if (m == 0) {
#pragma unroll
            for (int h = 0; h < 2; ++h) {
                const double* zr = &ybuf[(g * 2 + h) * 128 + l * 16];
                double dl_ = 0.0;
#pragma unroll
                for (int c = 0; c < 16; ++c) {
                    const double dd = zr[c] - zqd[h][c];
                    dl_ = fma(dd, dd, dl_);
                }
                acc_loss += dl_;
            }
        }
        // corrections: ybuf[tok][ii*16+b] -= sum_a zq[a] * G[l][ii][a][b], ii>l
        if (l < 7) {
            const int tokh = m >> 4, b = m & 15;
            double zsel[16];
#pragma unroll
            for (int a = 0; a < 16; ++a) zsel[a] = tokh ? zqd[1][a] : zqd[0][a];
            for (int ii = l + 1; ii < 8; ++ii) {
                const double* gp = G + (size_t)(l * 8 + ii) * 256 + b;
                double corr = 0.0;
#pragma unroll
                for (int a = 0; a < 16; ++a) corr = fma(zsel[a], gp[a * 16], corr);
                ybuf[(g * 2 + tokh) * 128 + ii * 16 + b] -= corr;
            }
        }
    }

    if (m == 0) lred[g] = acc_loss;
    __syncthreads();
    if (t == 0) {
        double s = 0.0;
#pragma unroll
        for (int gg = 0; gg < 8; ++gg) s += lred[gg];
        atomicAdd(wacc, s);
    }
}

__global__ void __launch_bounds__(64) rvq_fin(const double* __restrict__ wacc,
                                              float* __restrict__ lossp) {
    if (threadIdx.x == 0) {
        const float v = (float)(wacc[0] * (1.0 / 524288.0));
        lossp[0] = v; lossp[1] = v; lossp[2] = 0.0f;
    }
}

extern "C" void kernel_launch(void* const* d_in, const int* in_sizes, int n_in,
                              void* d_out, int out_size, void* d_ws, size_t ws_size,
                              hipStream_t stream) {
    (void)in_sizes; (void)n_in; (void)ws_size;
    const float* z_e = (const float*)d_in[0];
    const float* Wd  = (const float*)d_in[1];
    const float* bd  = (const float*)d_in[2];
    const float* cb  = (const float*)d_in[3];
    const float* Wu  = (const float*)d_in[4];
    const float* bu  = (const float*)d_in[5];

    float* out0  = (float*)d_out;                      // (8,4096,128)
    float* out1  = out0 + (size_t)8 * 4096 * 128;      // (8,4096,8) codes
    float* lossp = out0 + (size_t)out_size - 3;        // commit, cbl, entropy

    double* wsd = (double*)d_ws;
    double* wacc = wsd;
    double* cbn  = wsd + CBN_OFF;
    double* G    = wsd + G_OFF;
    double* hv   = wsd + HV_OFF;

    rvq_zero<<<1, 64, 0, stream>>>(wacc);
    rvq_prep_cbn<<<32, 256, 0, stream>>>(cb, cbn);
    rvq_prep_g<<<64, 256, 0, stream>>>(Wu, Wd, G);
    rvq_prep_h<<<1, 128, 0, stream>>>(Wd, bd, bu, hv);
    rvq_main<<<2048, 256, 0, stream>>>(z_e, Wd, cb, cbn, G, hv, wacc, out0, out1);
    rvq_fin<<<1, 64, 0, stream>>>(wacc, lossp);
}

// Round 3
// 1111.278 us; speedup vs baseline: 19.7322x; 19.7322x over previous
//
#include <hip/hip_runtime.h>
#include <math.h>

// ResidualVQ fused forward, MI355X (gfx950) — round 3.
// fp32 hot path + sound fp64 fallback for near-tie argmin decisions.
// z_i = z_e.WdT_i + hv_i - sum_{j<i} zq_j.G[j][i],  G[j][i]=WuT_j.WdT_i.
//
// Round-2 post-mortem: 33 GB scratch writes (VGPR live-set > 128 alloc).
// This round every phase keeps <= ~80 live VGPRs by construction.

#define TAU 3e-4f

// ws byte offsets (16B aligned)
#define WS_WACC   0
#define WS_HV64   64
#define WS_G64    2048
#define WS_CBN64  133120
#define WS_CBN32  1247232
#define WS_G32    1902592
#define WS_HV32   1968128
#define WS_BMAT   1968640

__global__ void __launch_bounds__(64) rvq_zero(double* w) {
    if (threadIdx.x == 0) w[0] = 0.0;
}

// normalized codebook: fp64 (stride 17: 16 + |c|^2) and fp32 (stride 20: 16 + |c|^2 + pad)
__global__ void __launch_bounds__(256) rvq_prep_cbn(const float* __restrict__ cb,
                                                    double* __restrict__ cbn64,
                                                    float* __restrict__ cbn32) {
    const int idx = blockIdx.x * 256 + threadIdx.x;   // l*1024+k
    const float* cp = cb + (size_t)idx * 16;
    double v[16]; double n = 0.0;
#pragma unroll
    for (int c = 0; c < 16; ++c) { v[c] = (double)cp[c]; n = fma(v[c], v[c], n); }
    const double iv = 1.0 / fmax(sqrt(n), 1e-12);
    double* r64 = cbn64 + (size_t)idx * 17;
    float*  r32 = cbn32 + (size_t)idx * 20;
    double c2 = 0.0;
#pragma unroll
    for (int c = 0; c < 16; ++c) {
        const double x = v[c] * iv;
        c2 = fma(x, x, c2);
        r64[c] = x; r32[c] = (float)x;
    }
    r64[16] = c2;
    r32[16] = (float)c2; r32[17] = 0.f; r32[18] = 0.f; r32[19] = 0.f;
}

// G[j][i][a][b] = sum_d Wu[j,d,a] * Wd[i,b,d]   (fp64 + fp32 copies)
__global__ void __launch_bounds__(256) rvq_prep_g(const float* __restrict__ Wu,
                                                  const float* __restrict__ Wd,
                                                  double* __restrict__ G64,
                                                  float* __restrict__ G32) {
    const int j = blockIdx.x >> 3, i = blockIdx.x & 7;
    if (j >= i) return;
    const int t = threadIdx.x, a = t >> 4, b = t & 15;
    const float* up = Wu + (size_t)j * 16384 + a;                 // stride 16
    const float* dp = Wd + (size_t)i * 16384 + (size_t)b * 1024;  // stride 1
    double s0 = 0, s1 = 0, s2 = 0, s3 = 0;
    for (int d = 0; d < 1024; d += 4) {
        s0 = fma((double)up[(d + 0) * 16], (double)dp[d + 0], s0);
        s1 = fma((double)up[(d + 1) * 16], (double)dp[d + 1], s1);
        s2 = fma((double)up[(d + 2) * 16], (double)dp[d + 2], s2);
        s3 = fma((double)up[(d + 3) * 16], (double)dp[d + 3], s3);
    }
    const double g = (s0 + s1) + (s2 + s3);
    G64[(size_t)(j * 8 + i) * 256 + t] = g;
    G32[(size_t)(j * 8 + i) * 256 + t] = (float)g;
}

// hv[i][b] = bd[i,b] - sum_d (sum_{j<i} bu[j,d]) * Wd[i,b,d]
__global__ void __launch_bounds__(128) rvq_prep_h(const float* __restrict__ Wd,
                                                  const float* __restrict__ bd,
                                                  const float* __restrict__ bu,
                                                  double* __restrict__ hv64,
                                                  float* __restrict__ hv32) {
    const int t = threadIdx.x, i = t >> 4, b = t & 15;
    const float* dp = Wd + (size_t)i * 16384 + (size_t)b * 1024;
    double s = 0.0;
    for (int d = 0; d < 1024; ++d) {
        double sb = 0.0;
        for (int j = 0; j < i; ++j) sb += (double)bu[j * 1024 + d];
        s = fma(sb, (double)dp[d], s);
    }
    const double h = (double)bd[t] - s;
    hv64[t] = h; hv32[t] = (float)h;
}

// Bmat[d][i*16+c] = Wd[i][c][d]   (1024 x 128 fp32)
__global__ void __launch_bounds__(256) rvq_prep_bmat(const float* __restrict__ Wd,
                                                     float* __restrict__ Bmat) {
    const int ic = blockIdx.x;           // 0..127 = i*16+c
    const int d0 = threadIdx.x * 4;
    const float4 v = *(const float4*)(Wd + (size_t)ic * 1024 + d0);
    Bmat[(size_t)(d0 + 0) * 128 + ic] = v.x;
    Bmat[(size_t)(d0 + 1) * 128 + ic] = v.y;
    Bmat[(size_t)(d0 + 2) * 128 + ic] = v.z;
    Bmat[(size_t)(d0 + 3) * 128 + ic] = v.w;
}

// Main fused kernel: 512 blocks x 256 threads, 64 tokens/block.
__global__ void __launch_bounds__(256, 2) rvq_main(
    const float* __restrict__ z_e, const float* __restrict__ Wd,
    const float* __restrict__ cb,
    const float* __restrict__ Bmat, const float* __restrict__ hv32,
    const double* __restrict__ hv64,
    const float* __restrict__ cbn32, const double* __restrict__ cbn64,
    const float* __restrict__ G32, const double* __restrict__ G64,
    double* __restrict__ wacc,
    float* __restrict__ out0, float* __restrict__ out1)
{
    __shared__ double stag_d[1600];        // 12800 B staging union
    __shared__ float ybuf[64 * 132];       // 33792 B (token stride 132)
    __shared__ float candd[512], candd2[512];
    __shared__ int   candk[512];
    __shared__ float zqs[64 * 17];
    __shared__ int   bkhist[512];
    __shared__ int   bks[64];
    __shared__ int   flist[64];
    __shared__ int   flagcnt;
    float* stag = reinterpret_cast<float*>(stag_d);

    const int t = threadIdx.x;
    const int tok0g = blockIdx.x * 64;

    // ================= fused GEMM: y = z_e . Bmat + hv =================
    {
        float* As = stag;                 // [16][68]
        float* Bs = stag + 1088;          // [16][132]
        const int ty = t >> 4, tx = t & 15;
        float acc[4][8];
#pragma unroll
        for (int i = 0; i < 4; ++i)
#pragma unroll
            for (int j = 0; j < 8; ++j) acc[i][j] = 0.f;

        for (int ko = 0; ko < 64; ++ko) {
            const int k0 = ko * 16;
            __syncthreads();
            {
                const int kk = t & 15, mb = t >> 4;
#pragma unroll
                for (int p = 0; p < 4; ++p) {
                    const int m = mb + 16 * p;
                    As[kk * 68 + m] = z_e[(size_t)(tok0g + m) * 1024 + k0 + kk];
                }
                const int kb = t >> 4, nb = (t & 15) * 8;
                const float4* bp = (const float4*)(Bmat + (size_t)(k0 + kb) * 128 + nb);
                *(float4*)&Bs[kb * 132 + nb]     = bp[0];
                *(float4*)&Bs[kb * 132 + nb + 4] = bp[1];
            }
            __syncthreads();
#pragma unroll
            for (int kk = 0; kk < 16; ++kk) {
                const float4 av = *(const float4*)&As[kk * 68 + ty * 4];
                const float4 b0 = *(const float4*)&Bs[kk * 132 + tx * 8];
                const float4 b1 = *(const float4*)&Bs[kk * 132 + tx * 8 + 4];
                const float a[4] = {av.x, av.y, av.z, av.w};
                const float bb[8] = {b0.x, b0.y, b0.z, b0.w, b1.x, b1.y, b1.z, b1.w};
#pragma unroll
                for (int i = 0; i < 4; ++i)
#pragma unroll
                    for (int j = 0; j < 8; ++j)
                        acc[i][j] = fmaf(a[i], bb[j], acc[i][j]);
            }
        }
        __syncthreads();
#pragma unroll
        for (int i = 0; i < 4; ++i) {
            float* yr = &ybuf[(ty * 4 + i) * 132 + tx * 8];
#pragma unroll
            for (int j = 0; j < 8; ++j) yr[j] = acc[i][j] + hv32[tx * 8 + j];
        }
    }

    // ================= layer loop =================
    double lacc = 0.0;
    const int cg = t >> 5, tp = t & 31;
#pragma unroll 1
    for (int l = 0; l < 8; ++l) {
        __syncthreads();
        // normalize this thread's two tokens (redundant across cg — cheap)
        float zn[2][16];
#pragma unroll
        for (int h = 0; h < 2; ++h) {
            const float* yr = &ybuf[(2 * tp + h) * 132 + l * 16];
            float yv[16]; float n2 = 0.f;
#pragma unroll
            for (int c = 0; c < 16; ++c) { yv[c] = yr[c]; n2 = fmaf(yv[c], yv[c], n2); }
            const float iv = 1.0f / fmaxf(sqrtf(n2), 1e-12f);
#pragma unroll
            for (int c = 0; c < 16; ++c) zn[h][c] = yv[c] * iv;
        }
        float bs0 = 1e30f, bs20 = 1e30f, bs1 = 1e30f, bs21 = 1e30f;
        int bk0 = -1, bk1 = -1;
#pragma unroll 1
        for (int cc = 0; cc < 8; ++cc) {
            __syncthreads();
            {   // stage 128 normalized code rows (20 floats each)
                const int row = t >> 1, half = t & 1;
                const float4* src = (const float4*)(cbn32 +
                    (size_t)(l * 1024 + cc * 128 + row) * 20);
                float4* dst = (float4*)&stag[row * 20];
                if (half == 0) { dst[0] = src[0]; dst[1] = src[1]; }
                else           { dst[2] = src[2]; dst[3] = src[3]; dst[4] = src[4]; }
            }
            __syncthreads();
#pragma unroll
            for (int kk = 0; kk < 16; ++kk) {
                const int ci = cg * 16 + kk;
                const float* row = &stag[ci * 20];
                const float4 c0 = *(const float4*)&row[0];
                const float4 c1 = *(const float4*)&row[4];
                const float4 c2 = *(const float4*)&row[8];
                const float4 c3 = *(const float4*)&row[12];
                const float cn2 = row[16];
                const float cf[16] = {c0.x,c0.y,c0.z,c0.w, c1.x,c1.y,c1.z,c1.w,
                                      c2.x,c2.y,c2.z,c2.w, c3.x,c3.y,c3.z,c3.w};
                float d0 = 0.f, d1 = 0.f;
#pragma unroll
                for (int c = 0; c < 16; ++c) {
                    d0 = fmaf(cf[c], zn[0][c], d0);
                    d1 = fmaf(cf[c], zn[1][c], d1);
                }
                const float s0 = fmaf(-2.f, d0, cn2);
                const float s1 = fmaf(-2.f, d1, cn2);
                const int k = cc * 128 + ci;
                // top-2 update (ascending k within thread, strict <)
                {
                    const bool w = s0 < bs0;
                    bs20 = w ? bs0 : fminf(bs20, s0);
                    bk0  = w ? k : bk0;
                    bs0  = w ? s0 : bs0;
                }
                {
                    const bool w = s1 < bs1;
                    bs21 = w ? bs1 : fminf(bs21, s1);
                    bk1  = w ? k : bk1;
                    bs1  = w ? s1 : bs1;
                }
            }
        }
        candd [cg * 64 + 2 * tp]     = bs0;
        candd2[cg * 64 + 2 * tp]     = bs20;
        candk [cg * 64 + 2 * tp]     = bk0;
        candd [cg * 64 + 2 * tp + 1] = bs1;
        candd2[cg * 64 + 2 * tp + 1] = bs21;
        candk [cg * 64 + 2 * tp + 1] = bk1;
        if (t == 0) flagcnt = 0;
        __syncthreads();
        if (t < 64) {   // per-token lexicographic top-2 merge over 8 code-groups
            float best = 1e30f, sec = 1e30f; int bk = -1;
#pragma unroll
            for (int c = 0; c < 8; ++c) {
                const float d  = candd [c * 64 + t];
                const float d2 = candd2[c * 64 + t];
                const int   k  = candk [c * 64 + t];
                const bool w = (d < best) || (d == best && k < bk);
                const float nw = fminf(sec, fminf(best, d2));
                const float nl = fminf(sec, d);
                sec  = w ? nw : nl;
                bk   = w ? k : bk;
                best = w ? d : best;
            }
            bks[t] = bk;
            const float* yr = &ybuf[t * 132 + l * 16];
            float n2 = 0.f;
#pragma unroll
            for (int c = 0; c < 16; ++c) n2 = fmaf(yr[c], yr[c], n2);
            const bool flag = (sec - best < TAU) || (n2 < 1e-3f);
            if (flag) { const int p = atomicAdd(&flagcnt, 1); flist[p] = t; }
        }
        __syncthreads();

        // ---- rare fp64 recheck of near-tie tokens (exact reference argmin) ----
        const int nf = flagcnt;
#pragma unroll 1
        for (int f = 0; f < nf; ++f) {
            const int tok = flist[f];
            double* rpd = stag_d;
            {
                const int c = t & 15, ch = t >> 4;
                const float* gz = z_e + (size_t)(tok0g + tok) * 1024 + ch * 64;
                const float* wp = Wd + ((size_t)l * 16 + c) * 1024 + ch * 64;
                double pd = 0.0;
                for (int dd = 0; dd < 64; ++dd)
                    pd = fma((double)gz[dd], (double)wp[dd], pd);
                rpd[c * 16 + ch] = pd;
            }
            __syncthreads();
            if (t < 16) {
                double y = hv64[l * 16 + t];
#pragma unroll
                for (int ch = 0; ch < 16; ++ch) y += rpd[t * 16 + ch];
                for (int j = 0; j < l; ++j) {
                    const int bkj = bkhist[tok * 8 + j];
                    const float* q = cb + ((size_t)j * 1024 + bkj) * 16;
                    const double* gp = G64 + (size_t)(j * 8 + l) * 256 + t;
                    double s = 0.0;
#pragma unroll
                    for (int a = 0; a < 16; ++a)
                        s = fma((double)q[a], gp[a * 16], s);
                    y -= s;
                }
                rpd[256 + t] = y;
            }
            __syncthreads();
            if (t == 0) {
                double n2 = 0.0;
#pragma unroll
                for (int c = 0; c < 16; ++c) n2 = fma(rpd[256 + c], rpd[256 + c], n2);
                const double iv = 1.0 / fmax(sqrt(n2), 1e-12);
#pragma unroll
                for (int c = 0; c < 16; ++c) rpd[272 + c] = rpd[256 + c] * iv;
            }
            __syncthreads();
            {
                double bd_ = 1e300; int bk_ = -1;
#pragma unroll
                for (int q = 0; q < 4; ++q) {
                    const int k = q * 256 + t;
                    const double* row = cbn64 + (size_t)(l * 1024 + k) * 17;
                    double dot = 0.0;
#pragma unroll
                    for (int c = 0; c < 16; ++c) dot = fma(row[c], rpd[272 + c], dot);
                    const double s = fma(-2.0, dot, row[16]);
                    if (s < bd_) { bd_ = s; bk_ = k; }
                }
                rpd[288 + t] = bd_;
                ((int*)&rpd[544])[t] = bk_;
            }
            __syncthreads();
            if (t == 0) {
                double bd_ = 1e300; int bk_ = -1;
                for (int i = 0; i < 256; ++i) {
                    const double d = rpd[288 + i];
                    const int k = ((int*)&rpd[544])[i];
                    if (d < bd_ || (d == bd_ && k < bk_)) { bd_ = d; bk_ = k; }
                }
                bks[tok] = bk_;
            }
            __syncthreads();
        }

        // ---- gather raw code, outputs, loss ----
        if (t < 64) {
            const int bk = bks[t];
            bkhist[t * 8 + l] = bk;
            const float4* qp = (const float4*)(cb + ((size_t)l * 1024 + bk) * 16);
            const float4 q0 = qp[0], q1 = qp[1], q2 = qp[2], q3 = qp[3];
            float* op = out0 + (size_t)(tok0g + t) * 128 + l * 16;
            ((float4*)op)[0] = q0; ((float4*)op)[1] = q1;
            ((float4*)op)[2] = q2; ((float4*)op)[3] = q3;
            out1[(size_t)(tok0g + t) * 8 + l] = (float)bk;
            const float qf[16] = {q0.x,q0.y,q0.z,q0.w, q1.x,q1.y,q1.z,q1.w,
                                  q2.x,q2.y,q2.z,q2.w, q3.x,q3.y,q3.z,q3.w};
#pragma unroll
            for (int a = 0; a < 16; ++a) zqs[t * 17 + a] = qf[a];
            const float* yr = &ybuf[t * 132 + l * 16];
#pragma unroll
            for (int c = 0; c < 16; ++c) {
                const float d = yr[c] - qf[c];
                lacc += (double)d * (double)d;
            }
        }
        __syncthreads();

        // ---- corrections: ybuf[tok][ii*16+b] -= sum_a zq[a]*G32[l][ii][a][b] ----
        if (l < 7) {
            {
                const int total = (7 - l) * 256;
                for (int idx = t; idx < total; idx += 256) {
                    const int ii = l + 1 + (idx >> 8);
                    stag[idx] = G32[(size_t)(l * 8 + ii) * 256 + (idx & 255)];
                }
            }
            __syncthreads();
            const int part = t >> 6, tok = t & 63;
            float zql[16];
#pragma unroll
            for (int a = 0; a < 16; ++a) zql[a] = zqs[tok * 17 + a];
            for (int ii = l + 1 + part; ii < 8; ii += 4) {
                const float* gb = &stag[(ii - l - 1) * 256];
                float corr[16];
#pragma unroll
                for (int b = 0; b < 16; ++b) corr[b] = 0.f;
#pragma unroll
                for (int a = 0; a < 16; ++a) {
                    const float4 g0 = *(const float4*)&gb[a * 16];
                    const float4 g1 = *(const float4*)&gb[a * 16 + 4];
                    const float4 g2 = *(const float4*)&gb[a * 16 + 8];
                    const float4 g3 = *(const float4*)&gb[a * 16 + 12];
                    const float za = zql[a];
                    corr[0]  = fmaf(za, g0.x, corr[0]);  corr[1]  = fmaf(za, g0.y, corr[1]);
                    corr[2]  = fmaf(za, g0.z, corr[2]);  corr[3]  = fmaf(za, g0.w, corr[3]);
                    corr[4]  = fmaf(za, g1.x, corr[4]);  corr[5]  = fmaf(za, g1.y, corr[5]);
                    corr[6]  = fmaf(za, g1.z, corr[6]);  corr[7]  = fmaf(za, g1.w, corr[7]);
                    corr[8]  = fmaf(za, g2.x, corr[8]);  corr[9]  = fmaf(za, g2.y, corr[9]);
                    corr[10] = fmaf(za, g2.z, corr[10]); corr[11] = fmaf(za, g2.w, corr[11]);
                    corr[12] = fmaf(za, g3.x, corr[12]); corr[13] = fmaf(za, g3.y, corr[13]);
                    corr[14] = fmaf(za, g3.z, corr[14]); corr[15] = fmaf(za, g3.w, corr[15]);
                }
                float* yr = &ybuf[tok * 132 + ii * 16];
#pragma unroll
                for (int v = 0; v < 4; ++v) {
                    float4 y4 = *(float4*)&yr[v * 4];
                    y4.x -= corr[v * 4 + 0]; y4.y -= corr[v * 4 + 1];
                    y4.z -= corr[v * 4 + 2]; y4.w -= corr[v * 4 + 3];
                    *(float4*)&yr[v * 4] = y4;
                }
            }
        }
    }

    // loss reduce (threads 0..63 are exactly wave 0)
    if (t < 64) {
#pragma unroll
        for (int off = 32; off > 0; off >>= 1) lacc += __shfl_down(lacc, off);
        if (t == 0) atomicAdd(wacc, lacc);
    }
}

__global__ void __launch_bounds__(64) rvq_fin(const double* __restrict__ wacc,
                                              float* __restrict__ lossp) {
    if (threadIdx.x == 0) {
        const float v = (float)(wacc[0] * (1.0 / 524288.0));
        lossp[0] = v; lossp[1] = v; lossp[2] = 0.0f;
    }
}

extern "C" void kernel_launch(void* const* d_in, const int* in_sizes, int n_in,
                              void* d_out, int out_size, void* d_ws, size_t ws_size,
                              hipStream_t stream) {
    (void)in_sizes; (void)n_in; (void)ws_size;
    const float* z_e = (const float*)d_in[0];
    const float* Wd  = (const float*)d_in[1];
    const float* bd  = (const float*)d_in[2];
    const float* cb  = (const float*)d_in[3];
    const float* Wu  = (const float*)d_in[4];
    const float* bu  = (const float*)d_in[5];

    float* out0  = (float*)d_out;                      // (8,4096,128)
    float* out1  = out0 + (size_t)8 * 4096 * 128;      // (8,4096,8) codes
    float* lossp = out0 + (size_t)out_size - 3;        // commit, cbl, entropy

    char* ws = (char*)d_ws;
    double* wacc  = (double*)(ws + WS_WACC);
    double* hv64  = (double*)(ws + WS_HV64);
    double* G64   = (double*)(ws + WS_G64);
    double* cbn64 = (double*)(ws + WS_CBN64);
    float*  cbn32 = (float*) (ws + WS_CBN32);
    float*  G32   = (float*) (ws + WS_G32);
    float*  hv32  = (float*) (ws + WS_HV32);
    float*  Bmat  = (float*) (ws + WS_BMAT);

    rvq_zero<<<1, 64, 0, stream>>>(wacc);
    rvq_prep_cbn<<<32, 256, 0, stream>>>(cb, cbn64, cbn32);
    rvq_prep_g<<<64, 256, 0, stream>>>(Wu, Wd, G64, G32);
    rvq_prep_h<<<1, 128, 0, stream>>>(Wd, bd, bu, hv64, hv32);
    rvq_prep_bmat<<<128, 256, 0, stream>>>(Wd, Bmat);
    rvq_main<<<512, 256, 0, stream>>>(z_e, Wd, cb, Bmat, hv32, hv64,
                                      cbn32, cbn64, G32, G64, wacc, out0, out1);
    rvq_fin<<<1, 64, 0, stream>>>(wacc, lossp);
}

// Round 4
// 861.279 us; speedup vs baseline: 25.4598x; 1.2903x over previous
//
#include <hip/hip_runtime.h>
#include <math.h>

// ResidualVQ fused forward, MI355X (gfx950) — round 4.
// z_i = z_e.WdT_i + hv_i - sum_{j<i} zq_j.G[j][i],  G[j][i]=WuT_j.WdT_i.
// fp32 hot path + TAU-guarded fp64 recheck (exact vs numpy argmin).
//
// R3 post-mortem: ~570us was prep kernels (1-block latency-bound rvq_prep_h);
// main at 540us had 2 blk/CU occupancy + 4-way LDS conflicts on the B-tile.
// R4: parallel preps (2 fused kernels), 32-tok blocks (3 blk/CU), conflict-free
// LDS strides, single normalize into LDS.

#define TAU 3e-4f

// ws byte offsets
#define WS_WACC   0
#define WS_HV64   64
#define WS_G64    2048
#define WS_CBN64  133120
#define WS_CBN32  1247232
#define WS_G32    1902592
#define WS_HV32   1968128
#define WS_BMAT   1968640
#define WS_SBU    2492928

// ============================ prep1 ============================
// blocks: [0,32) cbn | [32,160) bmat | [160,192) sbu | 192 zero
__global__ void __launch_bounds__(256) rvq_prep1(
    const float* __restrict__ cb, const float* __restrict__ Wd,
    const float* __restrict__ bu,
    double* __restrict__ cbn64, float* __restrict__ cbn32,
    float* __restrict__ Bmat, double* __restrict__ sbu,
    double* __restrict__ wacc)
{
    const int b = blockIdx.x, t = threadIdx.x;
    if (b < 32) {                       // normalized codebook fp64+fp32
        const int idx = b * 256 + t;    // l*1024+k
        const float* cp = cb + (size_t)idx * 16;
        double v[16]; double n = 0.0;
#pragma unroll
        for (int c = 0; c < 16; ++c) { v[c] = (double)cp[c]; n = fma(v[c], v[c], n); }
        const double iv = 1.0 / fmax(sqrt(n), 1e-12);
        double* r64 = cbn64 + (size_t)idx * 17;
        float*  r32 = cbn32 + (size_t)idx * 20;
        double c2 = 0.0;
#pragma unroll
        for (int c = 0; c < 16; ++c) {
            const double x = v[c] * iv;
            c2 = fma(x, x, c2);
            r64[c] = x; r32[c] = (float)x;
        }
        r64[16] = c2;
        r32[16] = (float)c2; r32[17] = 0.f; r32[18] = 0.f; r32[19] = 0.f;
    } else if (b < 160) {               // Bmat[d][ic] = Wd[ic][d]
        const int ic = b - 32;
        const int d0 = t * 4;
        const float4 v = *(const float4*)(Wd + (size_t)ic * 1024 + d0);
        Bmat[(size_t)(d0 + 0) * 128 + ic] = v.x;
        Bmat[(size_t)(d0 + 1) * 128 + ic] = v.y;
        Bmat[(size_t)(d0 + 2) * 128 + ic] = v.z;
        Bmat[(size_t)(d0 + 3) * 128 + ic] = v.w;
    } else if (b < 192) {               // sbu[i][d] = sum_{j<i} bu[j][d]
        const int idx = b - 160;        // 0..31
        const int i = idx >> 2, d = (idx & 3) * 256 + t;
        double s = 0.0;
        for (int j = 0; j < i; ++j) s += (double)bu[j * 1024 + d];
        sbu[i * 1024 + d] = s;
    } else {
        if (t == 0) wacc[0] = 0.0;
    }
}

// ============================ prep2 ============================
// blocks [0,64): G pair (j=b>>3, i=b&7, skip j>=i) | [64,72): hv row i=b-64
__global__ void __launch_bounds__(256) rvq_prep2(
    const float* __restrict__ Wu, const float* __restrict__ Wd,
    const float* __restrict__ bd, const double* __restrict__ sbu,
    double* __restrict__ G64, float* __restrict__ G32,
    double* __restrict__ hv64, float* __restrict__ hv32)
{
    __shared__ double sm2[1200];
    float* smf = (float*)sm2;
    const int b = blockIdx.x, t = threadIdx.x;
    if (b < 64) {
        const int j = b >> 3, i = b & 7;
        if (j >= i) return;
        float* Aus = smf;               // [64][20] Wu[j, d, a]
        float* Bds = smf + 1280;        // [16][68] Wd[i, b, d]
        const int a = t >> 4, bb = t & 15;
        double s = 0.0;
        for (int ch = 0; ch < 16; ++ch) {
            __syncthreads();
            {
                const int dd = t >> 2, a4 = (t & 3) * 4;
                const float4 v = *(const float4*)(Wu + (size_t)j * 16384
                                  + (size_t)(ch * 64 + dd) * 16 + a4);
                *(float4*)&Aus[dd * 20 + a4] = v;
                const int br = t >> 4, d4 = (t & 15) * 4;
                const float4 w = *(const float4*)(Wd + (size_t)i * 16384
                                  + (size_t)br * 1024 + ch * 64 + d4);
                *(float4*)&Bds[br * 68 + d4] = w;
            }
            __syncthreads();
#pragma unroll
            for (int dd = 0; dd < 64; ++dd)
                s = fma((double)Aus[dd * 20 + a], (double)Bds[bb * 68 + dd], s);
        }
        G64[(size_t)(j * 8 + i) * 256 + t] = s;
        G32[(size_t)(j * 8 + i) * 256 + t] = (float)s;
    } else {
        const int i = b - 64;
        const int dq = t >> 4, bb = t & 15;
        const double* sp = sbu + i * 1024 + dq * 64;
        const float*  wp = Wd + (size_t)i * 16384 + (size_t)bb * 1024 + dq * 64;
        double s = 0.0;
#pragma unroll
        for (int dd = 0; dd < 64; ++dd)
            s = fma(sp[dd], (double)wp[dd], s);
        sm2[dq * 20 + bb] = s;
        __syncthreads();
        if (t < 16) {
            double s2 = 0.0;
#pragma unroll
            for (int q = 0; q < 16; ++q) s2 += sm2[q * 20 + t];
            const double h = (double)bd[i * 16 + t] - s2;
            hv64[i * 16 + t] = h; hv32[i * 16 + t] = (float)h;
        }
    }
}

// ============================ main ============================
// 1024 blocks x 256 threads, 32 tokens/block, ~48KB LDS -> 3 blocks/CU.
__global__ void __launch_bounds__(256, 3) rvq_main(
    const float* __restrict__ z_e, const float* __restrict__ Wd,
    const float* __restrict__ cb,
    const float* __restrict__ Bmat, const float* __restrict__ hv32,
    const double* __restrict__ hv64,
    const float* __restrict__ cbn32, const double* __restrict__ cbn64,
    const float* __restrict__ G32, const double* __restrict__ G64,
    double* __restrict__ wacc,
    float* __restrict__ out0, float* __restrict__ out1)
{
    __shared__ double stag_d[2624];     // 21KB union: GEMM tiles / code chunks / G32 / recheck
    __shared__ float ybuf[32 * 132];    // 16.9KB
    __shared__ float znbuf[32 * 20];
    __shared__ float candd[512], candd2[512];
    __shared__ int   candk[512];
    __shared__ float zqs[32 * 17];
    __shared__ int   bkhist[256];
    __shared__ int   bks[32], flist[32];
    __shared__ int   flagcnt;
    float* stag = reinterpret_cast<float*>(stag_d);

    const int t = threadIdx.x;
    const int tok0g = blockIdx.x * 32;

    // ---------------- GEMM: y = z_e . Bmat + hv ----------------
    {
        float* As = stag;               // [16][36]
        float* Bs = stag + 640;         // [16][132]
        const int ty = t >> 4, tx = t & 15;
        float acc[2][8];
#pragma unroll
        for (int h = 0; h < 2; ++h)
#pragma unroll
            for (int j = 0; j < 8; ++j) acc[h][j] = 0.f;

#pragma unroll 1
        for (int ko = 0; ko < 64; ++ko) {
            const int k0 = ko * 16;
            __syncthreads();
            {   // A: 32 tok x 16 k
                const int m = t >> 3, kk2 = (t & 7) * 2;
                const float2 v = *(const float2*)(z_e +
                    (size_t)(tok0g + m) * 1024 + k0 + kk2);
                As[kk2 * 36 + m] = v.x;
                As[(kk2 + 1) * 36 + m] = v.y;
                // B: 16 k x 128 n
                const int kb = t >> 4, nb = (t & 15) * 8;
                const float4* bp = (const float4*)(Bmat + (size_t)(k0 + kb) * 128 + nb);
                *(float4*)&Bs[kb * 132 + nb]     = bp[0];
                *(float4*)&Bs[kb * 132 + nb + 4] = bp[1];
            }
            __syncthreads();
#pragma unroll
            for (int kk = 0; kk < 16; ++kk) {
                const float2 av = *(const float2*)&As[kk * 36 + ty * 2];
                const float4 b0 = *(const float4*)&Bs[kk * 132 + tx * 4];
                const float4 b1 = *(const float4*)&Bs[kk * 132 + 64 + tx * 4];
                const float bb[8] = {b0.x,b0.y,b0.z,b0.w, b1.x,b1.y,b1.z,b1.w};
#pragma unroll
                for (int j = 0; j < 8; ++j) {
                    acc[0][j] = fmaf(av.x, bb[j], acc[0][j]);
                    acc[1][j] = fmaf(av.y, bb[j], acc[1][j]);
                }
            }
        }
        __syncthreads();
#pragma unroll
        for (int h = 0; h < 2; ++h) {
            float* yr = &ybuf[(2 * ty + h) * 132];
#pragma unroll
            for (int x = 0; x < 4; ++x)
                yr[tx * 4 + x] = acc[h][x] + hv32[tx * 4 + x];
#pragma unroll
            for (int x = 0; x < 4; ++x)
                yr[64 + tx * 4 + x] = acc[h][4 + x] + hv32[64 + tx * 4 + x];
        }
    }

    // ---------------- layer loop ----------------
    double lacc = 0.0;
    const int cg = t >> 4, tp = t & 15;
#pragma unroll 1
    for (int l = 0; l < 8; ++l) {
        __syncthreads();
        if (t < 32) {                   // normalize token t once into LDS
            const float* yr = &ybuf[t * 132 + l * 16];
            float yv[16]; float n2 = 0.f;
#pragma unroll
            for (int c = 0; c < 16; ++c) { yv[c] = yr[c]; n2 = fmaf(yv[c], yv[c], n2); }
            const float iv = 1.0f / fmaxf(sqrtf(n2), 1e-12f);
#pragma unroll
            for (int c = 0; c < 16; ++c) znbuf[t * 20 + c] = yv[c] * iv;
        }
        __syncthreads();
        float zn[2][16];
#pragma unroll
        for (int h = 0; h < 2; ++h)
#pragma unroll
            for (int v = 0; v < 4; ++v)
                *(float4*)&zn[h][v * 4] =
                    *(const float4*)&znbuf[(2 * tp + h) * 20 + v * 4];

        float bs0 = 1e30f, bs20 = 1e30f, bs1 = 1e30f, bs21 = 1e30f;
        int bk0 = -1, bk1 = -1;
#pragma unroll 1
        for (int q = 0; q < 4; ++q) {
            __syncthreads();
            {   // stage 256 code rows (20 floats, stride-20 -> conflict-free)
                const float4* src = (const float4*)(cbn32 +
                    (size_t)(l * 1024 + q * 256 + t) * 20);
                float4* dst = (float4*)&stag[t * 20];
#pragma unroll
                for (int u = 0; u < 5; ++u) dst[u] = src[u];
            }
            __syncthreads();
#pragma unroll
            for (int kk = 0; kk < 16; ++kk) {
                const int ci = cg * 16 + kk;
                const float* row = &stag[ci * 20];
                const float4 c0 = *(const float4*)&row[0];
                const float4 c1 = *(const float4*)&row[4];
                const float4 c2 = *(const float4*)&row[8];
                const float4 c3 = *(const float4*)&row[12];
                const float cn2 = row[16];
                const float cf[16] = {c0.x,c0.y,c0.z,c0.w, c1.x,c1.y,c1.z,c1.w,
                                      c2.x,c2.y,c2.z,c2.w, c3.x,c3.y,c3.z,c3.w};
                float d0 = 0.f, d1 = 0.f;
#pragma unroll
                for (int c = 0; c < 16; ++c) {
                    d0 = fmaf(cf[c], zn[0][c], d0);
                    d1 = fmaf(cf[c], zn[1][c], d1);
                }
                const float s0 = fmaf(-2.f, d0, cn2);
                const float s1 = fmaf(-2.f, d1, cn2);
                const int k = q * 256 + ci;
                {
                    const bool w = s0 < bs0;
                    bs20 = w ? bs0 : fminf(bs20, s0);
                    bk0  = w ? k : bk0;
                    bs0  = w ? s0 : bs0;
                }
                {
                    const bool w = s1 < bs1;
                    bs21 = w ? bs1 : fminf(bs21, s1);
                    bk1  = w ? k : bk1;
                    bs1  = w ? s1 : bs1;
                }
            }
        }
        candd [cg * 32 + 2 * tp]     = bs0;
        candd2[cg * 32 + 2 * tp]     = bs20;
        candk [cg * 32 + 2 * tp]     = bk0;
        candd [cg * 32 + 2 * tp + 1] = bs1;
        candd2[cg * 32 + 2 * tp + 1] = bs21;
        candk [cg * 32 + 2 * tp + 1] = bk1;
        if (t == 0) flagcnt = 0;
        __syncthreads();
        if (t < 32) {                   // lexicographic top-2 merge over 16 groups
            float best = 1e30f, sec = 1e30f; int bk = -1;
#pragma unroll
            for (int c = 0; c < 16; ++c) {
                const float d  = candd [c * 32 + t];
                const float d2 = candd2[c * 32 + t];
                const int   k  = candk [c * 32 + t];
                const bool w = (d < best) || (d == best && k < bk);
                const float nw = fminf(sec, fminf(best, d2));
                const float nl = fminf(sec, d);
                sec  = w ? nw : nl;
                bk   = w ? k : bk;
                best = w ? d : best;
            }
            bks[t] = bk;
            const float* yr = &ybuf[t * 132 + l * 16];
            float n2 = 0.f;
#pragma unroll
            for (int c = 0; c < 16; ++c) n2 = fmaf(yr[c], yr[c], n2);
            if ((sec - best < TAU) || (n2 < 1e-3f)) {
                const int p = atomicAdd(&flagcnt, 1); flist[p] = t;
            }
        }
        __syncthreads();

        // ---- rare fp64 recheck (exact reference argmin) ----
        const int nf = flagcnt;
#pragma unroll 1
        for (int f = 0; f < nf; ++f) {
            const int tok = flist[f];
            double* rpd = stag_d;
            {
                const int c = t & 15, ch = t >> 4;
                const float* gz = z_e + (size_t)(tok0g + tok) * 1024 + ch * 64;
                const float* wp = Wd + ((size_t)l * 16 + c) * 1024 + ch * 64;
                double pd = 0.0;
                for (int dd = 0; dd < 64; ++dd)
                    pd = fma((double)gz[dd], (double)wp[dd], pd);
                rpd[c * 16 + ch] = pd;
            }
            __syncthreads();
            if (t < 16) {
                double y = hv64[l * 16 + t];
#pragma unroll
                for (int ch = 0; ch < 16; ++ch) y += rpd[t * 16 + ch];
                for (int j = 0; j < l; ++j) {
                    const int bkj = bkhist[tok * 8 + j];
                    const float* qv = cb + ((size_t)j * 1024 + bkj) * 16;
                    const double* gp = G64 + (size_t)(j * 8 + l) * 256 + t;
                    double s = 0.0;
#pragma unroll
                    for (int a = 0; a < 16; ++a)
                        s = fma((double)qv[a], gp[a * 16], s);
                    y -= s;
                }
                rpd[256 + t] = y;
            }
            __syncthreads();
            if (t == 0) {
                double n2 = 0.0;
#pragma unroll
                for (int c = 0; c < 16; ++c) n2 = fma(rpd[256 + c], rpd[256 + c], n2);
                const double iv = 1.0 / fmax(sqrt(n2), 1e-12);
#pragma unroll
                for (int c = 0; c < 16; ++c) rpd[272 + c] = rpd[256 + c] * iv;
            }
            __syncthreads();
            {
                double bd_ = 1e300; int bk_ = -1;
#pragma unroll
                for (int q = 0; q < 4; ++q) {
                    const int k = q * 256 + t;
                    const double* row = cbn64 + (size_t)(l * 1024 + k) * 17;
                    double dot = 0.0;
#pragma unroll
                    for (int c = 0; c < 16; ++c) dot = fma(row[c], rpd[272 + c], dot);
                    const double s = fma(-2.0, dot, row[16]);
                    if (s < bd_) { bd_ = s; bk_ = k; }
                }
                rpd[288 + t] = bd_;
                ((int*)&rpd[544])[t] = bk_;
            }
            __syncthreads();
            if (t == 0) {
                double bd_ = 1e300; int bk_ = -1;
                for (int i = 0; i < 256; ++i) {
                    const double d = rpd[288 + i];
                    const int k = ((int*)&rpd[544])[i];
                    if (d < bd_ || (d == bd_ && k < bk_)) { bd_ = d; bk_ = k; }
                }
                bks[tok] = bk_;
            }
            __syncthreads();
        }

        // ---- outputs, loss ----
        if (t < 32) {
            const int bk = bks[t];
            bkhist[t * 8 + l] = bk;
            const float4* qp = (const float4*)(cb + ((size_t)l * 1024 + bk) * 16);
            const float4 q0 = qp[0], q1 = qp[1], q2 = qp[2], q3 = qp[3];
            float* op = out0 + (size_t)(tok0g + t) * 128 + l * 16;
            ((float4*)op)[0] = q0; ((float4*)op)[1] = q1;
            ((float4*)op)[2] = q2; ((float4*)op)[3] = q3;
            out1[(size_t)(tok0g + t) * 8 + l] = (float)bk;
            const float qf[16] = {q0.x,q0.y,q0.z,q0.w, q1.x,q1.y,q1.z,q1.w,
                                  q2.x,q2.y,q2.z,q2.w, q3.x,q3.y,q3.z,q3.w};
#pragma unroll
            for (int a = 0; a < 16; ++a) zqs[t * 17 + a] = qf[a];
            const float* yr = &ybuf[t * 132 + l * 16];
#pragma unroll
            for (int c = 0; c < 16; ++c) {
                const float d = yr[c] - qf[c];
                lacc += (double)d * (double)d;
            }
        }
        __syncthreads();

        // ---- corrections: ybuf[tok][ii*16+b] -= sum_a zq[a]*G32[l][ii][a][b] ----
        if (l < 7) {
            {
                const int total = (7 - l) * 256;
                for (int idx = t; idx < total; idx += 256) {
                    const int ii = l + 1 + (idx >> 8);
                    stag[idx] = G32[(size_t)(l * 8 + ii) * 256 + (idx & 255)];
                }
            }
            __syncthreads();
            const int part = t >> 5, tok = t & 31;
            const int ii = l + 1 + part;
            if (ii < 8) {
                float zql[16];
#pragma unroll
                for (int a = 0; a < 16; ++a) zql[a] = zqs[tok * 17 + a];
                const float* gb = &stag[part * 256];
                float corr[16];
#pragma unroll
                for (int x = 0; x < 16; ++x) corr[x] = 0.f;
#pragma unroll
                for (int a = 0; a < 16; ++a) {
                    const float4 g0 = *(const float4*)&gb[a * 16];
                    const float4 g1 = *(const float4*)&gb[a * 16 + 4];
                    const float4 g2 = *(const float4*)&gb[a * 16 + 8];
                    const float4 g3 = *(const float4*)&gb[a * 16 + 12];
                    const float za = zql[a];
                    corr[0]  = fmaf(za, g0.x, corr[0]);  corr[1]  = fmaf(za, g0.y, corr[1]);
                    corr[2]  = fmaf(za, g0.z, corr[2]);  corr[3]  = fmaf(za, g0.w, corr[3]);
                    corr[4]  = fmaf(za, g1.x, corr[4]);  corr[5]  = fmaf(za, g1.y, corr[5]);
                    corr[6]  = fmaf(za, g1.z, corr[6]);  corr[7]  = fmaf(za, g1.w, corr[7]);
                    corr[8]  = fmaf(za, g2.x, corr[8]);  corr[9]  = fmaf(za, g2.y, corr[9]);
                    corr[10] = fmaf(za, g2.z, corr[10]); corr[11] = fmaf(za, g2.w, corr[11]);
                    corr[12] = fmaf(za, g3.x, corr[12]); corr[13] = fmaf(za, g3.y, corr[13]);
                    corr[14] = fmaf(za, g3.z, corr[14]); corr[15] = fmaf(za, g3.w, corr[15]);
                }
                float* yr = &ybuf[tok * 132 + ii * 16];
#pragma unroll
                for (int v = 0; v < 4; ++v) {
                    float4 y4 = *(float4*)&yr[v * 4];
                    y4.x -= corr[v * 4 + 0]; y4.y -= corr[v * 4 + 1];
                    y4.z -= corr[v * 4 + 2]; y4.w -= corr[v * 4 + 3];
                    *(float4*)&yr[v * 4] = y4;
                }
            }
        }
    }

    if (t < 64) {
#pragma unroll
        for (int off = 32; off > 0; off >>= 1) lacc += __shfl_down(lacc, off);
        if (t == 0) atomicAdd(wacc, lacc);
    }
}

__global__ void __launch_bounds__(64) rvq_fin(const double* __restrict__ wacc,
                                              float* __restrict__ lossp) {
    if (threadIdx.x == 0) {
        const float v = (float)(wacc[0] * (1.0 / 524288.0));
        lossp[0] = v; lossp[1] = v; lossp[2] = 0.0f;
    }
}

extern "C" void kernel_launch(void* const* d_in, const int* in_sizes, int n_in,
                              void* d_out, int out_size, void* d_ws, size_t ws_size,
                              hipStream_t stream) {
    (void)in_sizes; (void)n_in; (void)ws_size;
    const float* z_e = (const float*)d_in[0];
    const float* Wd  = (const float*)d_in[1];
    const float* bd  = (const float*)d_in[2];
    const float* cb  = (const float*)d_in[3];
    const float* Wu  = (const float*)d_in[4];
    const float* bu  = (const float*)d_in[5];

    float* out0  = (float*)d_out;                      // (8,4096,128)
    float* out1  = out0 + (size_t)8 * 4096 * 128;      // (8,4096,8) codes
    float* lossp = out0 + (size_t)out_size - 3;        // commit, cbl, entropy

    char* ws = (char*)d_ws;
    double* wacc  = (double*)(ws + WS_WACC);
    double* hv64  = (double*)(ws + WS_HV64);
    double* G64   = (double*)(ws + WS_G64);
    double* cbn64 = (double*)(ws + WS_CBN64);
    float*  cbn32 = (float*) (ws + WS_CBN32);
    float*  G32   = (float*) (ws + WS_G32);
    float*  hv32  = (float*) (ws + WS_HV32);
    float*  Bmat  = (float*) (ws + WS_BMAT);
    double* sbu   = (double*)(ws + WS_SBU);

    rvq_prep1<<<193, 256, 0, stream>>>(cb, Wd, bu, cbn64, cbn32, Bmat, sbu, wacc);
    rvq_prep2<<<72, 256, 0, stream>>>(Wu, Wd, bd, sbu, G64, G32, hv64, hv32);
    rvq_main<<<1024, 256, 0, stream>>>(z_e, Wd, cb, Bmat, hv32, hv64,
                                       cbn32, cbn64, G32, G64, wacc, out0, out1);
    rvq_fin<<<1, 64, 0, stream>>>(wacc, lossp);
}